// Round 1
// 414.451 us; speedup vs baseline: 1.7392x; 1.7392x over previous
//
#include <hip/hip_runtime.h>
#include <math.h>

// Problem constants
#define NVEC  32768          // B*L = 64*512
#define DDIM  512            // CODE_DIM
#define KCB   4              // NUM_CODEBOOKS
#define SCB   1024           // CODEBOOK_SIZE
#define SUBD  128            // SUB_DIM

#define IDX_COUNT (NVEC * KCB)            // 131072
#define ZQ_COUNT  (NVEC * DDIM)           // 16777216
#define OFF_ZQ_ST  IDX_COUNT
#define OFF_ZQ_ALL (IDX_COUNT + ZQ_COUNT)
#define OFF_SCAL   (IDX_COUNT + 2 * ZQ_COUNT)

// Scratch layout inside the z_q_all output region (all consumed before
// k_gather overwrites it; d_ws unused):
//   counts : int  [4096]              at zq_all + 0       (floats)
//   c2s    : f32  [4096] (scaled 2^20) at zq_all + 4096
//   c2np   : f32  [4096] (np-exact)    at zq_all + 8192
//   cb16   : fp16 [4096][128] (x1024)  at zq_all + 12288   (1 MB)
//   cand   : u16  [131072][8]          at zq_all + 274432  (2 MB)

typedef _Float16 v2h __attribute__((ext_vector_type(2)));
typedef _Float16 f16x8 __attribute__((ext_vector_type(8)));
typedef float f32x16 __attribute__((ext_vector_type(16)));
union U32H2 { unsigned int u; v2h h; };

// Strict (non-contractable) f32 ops replicating numpy's rounding exactly.
__device__ __forceinline__ float fmul(float a, float b) { return __fmul_rn(a, b); }
__device__ __forceinline__ float fadd(float a, float b) { return __fadd_rn(a, b); }
__device__ __forceinline__ float fsub(float a, float b) { return __fsub_rn(a, b); }

// numpy pairwise_sum for n=128 (scalar 8-accumulator path); elements are
// individually-rounded f32 products. Validated in round 4 (PASS).
__device__ __forceinline__ float np_dot128(const float* __restrict__ u,
                                           const float* __restrict__ v) {
  float r[8];
#pragma unroll
  for (int j = 0; j < 8; ++j) r[j] = fmul(u[j], v[j]);
#pragma unroll
  for (int i = 8; i < 128; i += 8) {
#pragma unroll
    for (int j = 0; j < 8; ++j) r[j] = fadd(r[j], fmul(u[i + j], v[i + j]));
  }
  return fadd(fadd(fadd(r[0], r[1]), fadd(r[2], r[3])),
              fadd(fadd(r[4], r[5]), fadd(r[6], r[7])));
}

// ---------------------------------------------------------------------------
// k_convert: codebook f32 -> fp16 (x1024, kills subnormals) + approx C2*2^20.
// One wave per 16 codes; lanes split the 128 dims (2 each).
// ---------------------------------------------------------------------------
__global__ __launch_bounds__(256) void k_convert(
    const float* __restrict__ cb, unsigned int* __restrict__ cb16,
    float* __restrict__ c2s) {
  const int wave = blockIdx.x * 4 + (threadIdx.x >> 6);
  const int lane = threadIdx.x & 63;
  for (int i = 0; i < 16; ++i) {
    const int code = wave * 16 + i;   // 0..4095
    const float2 v = ((const float2*)(cb + (size_t)code * SUBD))[lane];
    float tot = fmaf(v.x, v.x, v.y * v.y);
#pragma unroll
    for (int off = 32; off > 0; off >>= 1) tot += __shfl_down(tot, off, 64);
    v2h h; h.x = (_Float16)(v.x * 1024.0f); h.y = (_Float16)(v.y * 1024.0f);
    U32H2 t; t.h = h;
    cb16[(size_t)code * 64 + lane] = t.u;
    if (lane == 0) c2s[code] = tot * 1048576.0f;  // * 2^20
  }
}

// ---------------------------------------------------------------------------
// k_c2np: np-exact ||c||^2 per code (same tree as round-4's rescore).
// ---------------------------------------------------------------------------
__global__ __launch_bounds__(256) void k_c2np(const float* __restrict__ cb,
                                              float* __restrict__ c2np) {
  const int c = blockIdx.x * 256 + threadIdx.x;  // 0..4095
  const float* row = cb + (size_t)c * SUBD;
  c2np[c] = np_dot128(row, row);
}

// ---------------------------------------------------------------------------
// k_scan (MFMA rewrite): D = A*B with A = codebook tile rows (32 codes),
// B = z_e columns (32 vectors), K = 128 via 8x mfma_f32_32x32x16_f16.
// Block = 4 waves x 32 n = 128 vectors, one codebook k, all 1024 codes.
// C/D layout: col = lane&31 (one n per lane); rows split across the lane
// pair (hi = lane>>5) into two disjoint 512-code subsets -> each lane keeps
// a private top-4, pair writes 4+4 = 8 candidates per (n,k), same rescue
// guarantee as the old two-half scheme. Same cb16 (x1024 f16), same RTNE x
// conversion, same scaled score 2^20*(C2 - 2*dot) as the validated kernel.
// Codebook staged via LDS in 64-code (16 KB) double-buffered tiles with an
// XOR-16 slot swizzle (slot ^= row&15) so stride-256B ds_read_b128 A-frag
// reads are bank-conflict-free.
// ---------------------------------------------------------------------------
#define SCORE_HALF(ACC, STOFF)                                             \
  {                                                                        \
    _Pragma("unroll")                                                      \
    for (int g = 0; g < 4; ++g) {                                          \
      const float4 cv = *(const float4*)(c2b + (STOFF) + hi * 4 + g * 8);  \
      const float ca[4] = {cv.x, cv.y, cv.z, cv.w};                        \
      _Pragma("unroll")                                                    \
      for (int r = 0; r < 4; ++r) {                                        \
        const float score = fmaf(-2048.0f, (ACC)[g * 4 + r], ca[r]);       \
        const int s = tb + (STOFF) + hi * 4 + g * 8 + r;                   \
        if (score < m3) {                                                  \
          if (score < m0)      { m3=m2;i3=i2; m2=m1;i2=i1; m1=m0;i1=i0; m0=score;i0=s; } \
          else if (score < m1) { m3=m2;i3=i2; m2=m1;i2=i1; m1=score;i1=s; } \
          else if (score < m2) { m3=m2;i3=i2; m2=score;i2=s; }             \
          else                 { m3=score;i3=s; }                          \
        }                                                                  \
      }                                                                    \
    }                                                                      \
  }

__global__ __launch_bounds__(256) void k_scan(
    const float* __restrict__ z_e, const unsigned int* __restrict__ cb16,
    const float* __restrict__ c2s, unsigned short* __restrict__ cand) {
  const int tid = threadIdx.x;
  const int lane = tid & 63;
  const int w = tid >> 6;
  const int hi = lane >> 5;          // row-half of the lane pair
  const int ml = lane & 31;          // n-column within the wave tile
  const int k = blockIdx.y;
  const int n = blockIdx.x * 128 + w * 32 + ml;

  __shared__ __align__(16) unsigned int ctile[2][4096];  // 2 x 16 KB (64 codes)
  __shared__ __align__(16) float c2l[SCB];               // 4 KB

  const uint4* gk = (const uint4*)cb16 + (size_t)k * SCB * 16;
  const int rbase = tid >> 4;                 // staging row low bits
  const int ss = (tid & 15) ^ rbase;          // pre-swizzled source slot

  // B fragments: xf[ks][j] = f16(x[n][ks*16 + hi*8 + j])  (RTNE, unscaled)
  f16x8 xf[8];
  {
    const float* xp = z_e + (size_t)n * DDIM + k * SUBD + hi * 8;
#pragma unroll
    for (int ks = 0; ks < 8; ++ks) {
      const float4 a = *(const float4*)(xp + ks * 16);
      const float4 b = *(const float4*)(xp + ks * 16 + 4);
      f16x8 h;
      h[0] = (_Float16)a.x; h[1] = (_Float16)a.y;
      h[2] = (_Float16)a.z; h[3] = (_Float16)a.w;
      h[4] = (_Float16)b.x; h[5] = (_Float16)b.y;
      h[6] = (_Float16)b.z; h[7] = (_Float16)b.w;
      xf[ks] = h;
    }
  }

  // Stage c2 (whole k) + tile 0. LDS[row][p] = global[row][p ^ (row&15)],
  // so reading LDS[row][slot ^ (row&15)] returns linear global data.
  for (int i = tid; i < SCB; i += 256) c2l[i] = c2s[k * SCB + i];
  {
    uint4* dst = (uint4*)ctile[0];
#pragma unroll
    for (int p = 0; p < 4; ++p)
      dst[p * 256 + tid] = gk[(p * 16 + rbase) * 16 + ss];
  }
  __syncthreads();

  float m0 = 1e30f, m1 = 1e30f, m2 = 1e30f, m3 = 1e30f;
  int i0 = 0, i1 = 0, i2 = 0, i3 = 0;

  for (int tile = 0; tile < 16; ++tile) {
    // Issue next-tile global loads early (L2-hit; lands before ds_write).
    uint4 pf0, pf1, pf2, pf3;
    if (tile < 15) {
      const uint4* gt = gk + (size_t)(tile + 1) * 1024;
      pf0 = gt[(0 * 16 + rbase) * 16 + ss];
      pf1 = gt[(1 * 16 + rbase) * 16 + ss];
      pf2 = gt[(2 * 16 + rbase) * 16 + ss];
      pf3 = gt[(3 * 16 + rbase) * 16 + ss];
    }

    const unsigned char* bufb = (const unsigned char*)ctile[tile & 1];
    f32x16 acc0, acc1;
#pragma unroll
    for (int z = 0; z < 16; ++z) { acc0[z] = 0.0f; acc1[z] = 0.0f; }

    // Two independent 32-code MFMA chains (stile 0: rows 0..31, stile 1:
    // rows 32..63) for ILP. A-frag: row = stile*32 + ml, logical 16B slot
    // = ks*2 + hi, phys slot = slot ^ (row&15) = slot ^ (lane&15).
#pragma unroll
    for (int ks = 0; ks < 8; ++ks) {
      const int phys = (((ks * 2 + hi) ^ (lane & 15)) << 4);
      const f16x8 a0 = *(const f16x8*)(bufb + ml * 256 + phys);
      const f16x8 a1 = *(const f16x8*)(bufb + (ml + 32) * 256 + phys);
      acc0 = __builtin_amdgcn_mfma_f32_32x32x16_f16(a0, xf[ks], acc0, 0, 0, 0);
      acc1 = __builtin_amdgcn_mfma_f32_32x32x16_f16(a1, xf[ks], acc1, 0, 0, 0);
    }

    // Scores: acc reg -> code row = (reg&3) + 8*(reg>>2) + 4*hi (m74/m101).
    const int tb = tile * 64;
    const float* c2b = c2l + tb;
    SCORE_HALF(acc0, 0)
    SCORE_HALF(acc1, 32)

    if (tile < 15) {
      uint4* dst = (uint4*)ctile[(tile + 1) & 1];
      dst[0 * 256 + tid] = pf0;
      dst[1 * 256 + tid] = pf1;
      dst[2 * 256 + tid] = pf2;
      dst[3 * 256 + tid] = pf3;
    }
    __syncthreads();
  }

  // Lane pair (hi=0/1) covers disjoint 512-code subsets; write 4+4 = 8
  // candidates per (n,k), same buffer/semantics k_merge already consumes.
  const unsigned long long pk =
      (unsigned long long)(unsigned short)i0 |
      ((unsigned long long)(unsigned short)i1 << 16) |
      ((unsigned long long)(unsigned short)i2 << 32) |
      ((unsigned long long)(unsigned short)i3 << 48);
  *(unsigned long long*)(cand + ((size_t)(n * KCB + k)) * 8 + hi * 4) = pk;
}

// ---------------------------------------------------------------------------
// k_merge: np-exact f32 rescore of the 8 candidates per (n,k); same formula/
// tree as round 4 (validated). Writes final index + counts.
// ---------------------------------------------------------------------------
__global__ __launch_bounds__(256) void k_merge(
    const float* __restrict__ z_e, const float* __restrict__ cb,
    const unsigned short* __restrict__ cand, const float* __restrict__ c2np,
    float* __restrict__ out_idx, int* __restrict__ counts) {
  const int g = blockIdx.x * 256 + threadIdx.x;  // 0..131071
  const int n = g >> 2, k = g & 3;

  float4 xv[32];
  const float4* xp = (const float4*)(z_e + (size_t)n * DDIM + k * SUBD);
#pragma unroll
  for (int j = 0; j < 32; ++j) xv[j] = xp[j];
  const float* xs = (const float*)xv;
  const float A = np_dot128(xs, xs);

  const unsigned short* cp = cand + (size_t)g * 8;
  float bd = 1e30f;
  int bi = SCB;
#pragma unroll
  for (int t = 0; t < 8; ++t) {
    const int s = cp[t];
    const float* c = cb + (size_t)(k * SCB + s) * SUBD;
    const float E = np_dot128(xs, c);
    const float dist = fadd(fsub(A, fmul(2.0f, E)), c2np[k * SCB + s]);
    if (dist < bd || (dist == bd && s < bi)) { bd = dist; bi = s; }
  }

  out_idx[g] = (float)bi;
  atomicAdd(&counts[k * SCB + bi], 1);
}

// ---------------------------------------------------------------------------
// k_perp: perplexity from counts (before k_gather overwrites counts region).
// ---------------------------------------------------------------------------
__global__ __launch_bounds__(256) void k_perp(const int* __restrict__ counts,
                                              float* __restrict__ out_perp) {
  const int w = threadIdx.x >> 6;
  const int lane = threadIdx.x & 63;
  double h = 0.0;
  for (int i = 0; i < SCB / 64; ++i) {
    const int cnt = counts[w * SCB + i * 64 + lane];
    if (cnt > 0) {
      const double p = (double)cnt * (1.0 / 32768.0);
      h += p * log(p);
    }
  }
#pragma unroll
  for (int off = 32; off > 0; off >>= 1) h += __shfl_down(h, off, 64);
  __shared__ double hs[4];
  if (lane == 0) hs[w] = h;
  __syncthreads();
  if (threadIdx.x == 0) {
    double perp = 0.0;
    for (int w2 = 0; w2 < 4; ++w2) perp += exp(-hs[w2]);
    out_perp[0] = (float)(perp * 0.25);
  }
}

// ---------------------------------------------------------------------------
// k_gather: coalesced gather of z_q into both output slots + loss partial.
// ---------------------------------------------------------------------------
__global__ __launch_bounds__(256) void k_gather(
    const float* __restrict__ z_e, const float* __restrict__ cb,
    const float* __restrict__ idxf, float* __restrict__ zq_st,
    float* __restrict__ zq_all, float* __restrict__ loss_acc) {
  const int base = blockIdx.x * 4096;
  float local = 0.f;
#pragma unroll
  for (int i = 0; i < 16; ++i) {
    const int q = base + i * 256 + threadIdx.x;
    const int nn = q >> 7;
    const int rem = q & 127;
    const int kk = rem >> 5;
    const int j4 = rem & 31;
    const int idx = (int)idxf[nn * KCB + kk];
    const float4 v = ((const float4*)cb)[(size_t)(kk * SCB + idx) * 32 + j4];
    ((float4*)zq_st)[q] = v;
    ((float4*)zq_all)[q] = v;
    const float4 z = ((const float4*)z_e)[q];
    const float dx = z.x - v.x, dy = z.y - v.y, dz = z.z - v.z, dw = z.w - v.w;
    local += dx * dx + dy * dy + dz * dz + dw * dw;
  }
#pragma unroll
  for (int off = 32; off > 0; off >>= 1) local += __shfl_down(local, off, 64);
  __shared__ float red[4];
  const int w = threadIdx.x >> 6, lane = threadIdx.x & 63;
  if (lane == 0) red[w] = local;
  __syncthreads();
  if (threadIdx.x == 0) atomicAdd(loss_acc, (red[0] + red[1]) + (red[2] + red[3]));
}

__global__ void k_scal(float* __restrict__ scal) {
  if (threadIdx.x == 0) {
    const float m = scal[0] * (1.0f / 16777216.0f);
    scal[0] = m;   // codebook_loss
    scal[1] = m;   // commit_loss
  }
}

extern "C" void kernel_launch(void* const* d_in, const int* in_sizes, int n_in,
                              void* d_out, int out_size, void* d_ws, size_t ws_size,
                              hipStream_t stream) {
  const float* z_e = (const float*)d_in[0];
  const float* cb = (const float*)d_in[1];
  float* out = (float*)d_out;

  float* zq_all = out + OFF_ZQ_ALL;
  int* counts = (int*)zq_all;
  float* c2s = zq_all + 4096;
  float* c2np = zq_all + 8192;
  unsigned int* cb16 = (unsigned int*)(zq_all + 12288);
  unsigned short* cand = (unsigned short*)(zq_all + 274432);
  float* scal = out + OFF_SCAL;

  hipMemsetAsync(counts, 0, KCB * SCB * sizeof(int), stream);
  hipMemsetAsync(scal, 0, 3 * sizeof(float), stream);

  k_convert<<<64, 256, 0, stream>>>(cb, cb16, c2s);
  k_c2np<<<16, 256, 0, stream>>>(cb, c2np);
  dim3 gs(NVEC / 128, KCB);
  k_scan<<<gs, 256, 0, stream>>>(z_e, cb16, c2s, cand);
  k_merge<<<IDX_COUNT / 256, 256, 0, stream>>>(z_e, cb, cand, c2np, out, counts);
  k_perp<<<1, 256, 0, stream>>>(counts, scal + 2);
  k_gather<<<1024, 256, 0, stream>>>(z_e, cb, out, out + OFF_ZQ_ST, zq_all, scal);
  k_scal<<<1, 64, 0, stream>>>(scal);
}

// Round 2
// 386.084 us; speedup vs baseline: 1.8670x; 1.0735x over previous
//
#include <hip/hip_runtime.h>
#include <math.h>

// Problem constants
#define NVEC  32768          // B*L = 64*512
#define DDIM  512            // CODE_DIM
#define KCB   4              // NUM_CODEBOOKS
#define SCB   1024           // CODEBOOK_SIZE
#define SUBD  128            // SUB_DIM

#define IDX_COUNT (NVEC * KCB)            // 131072
#define ZQ_COUNT  (NVEC * DDIM)           // 16777216
#define OFF_ZQ_ST  IDX_COUNT
#define OFF_ZQ_ALL (IDX_COUNT + ZQ_COUNT)
#define OFF_SCAL   (IDX_COUNT + 2 * ZQ_COUNT)

// Scratch layout inside the z_q_all output region (all consumed before
// k_gather overwrites it; d_ws unused):
//   counts : int  [4096]               at zq_all + 0       (floats)
//   c2s    : f32  [4096] (scaled 2^20) at zq_all + 4096
//   c2np   : f32  [4096] (np-exact)    at zq_all + 8192
//   cb16   : fp16 [4096][128] (x1024)  at zq_all + 12288   (1 MB, ends 274432)
//   cand   : u16  [131072][8]          at zq_all + 274432  (2 MB, ends 798720)
//   ctrs   : int  [2]                  at zq_all + 800000

typedef _Float16 v2h __attribute__((ext_vector_type(2)));
typedef _Float16 f16x8 __attribute__((ext_vector_type(8)));
typedef float f32x16 __attribute__((ext_vector_type(16)));
union U32H2 { unsigned int u; v2h h; };

// Strict (non-contractable) f32 ops replicating numpy's rounding exactly.
__device__ __forceinline__ float fmul(float a, float b) { return __fmul_rn(a, b); }
__device__ __forceinline__ float fadd(float a, float b) { return __fadd_rn(a, b); }
__device__ __forceinline__ float fsub(float a, float b) { return __fsub_rn(a, b); }

// numpy pairwise_sum for n=128 (scalar 8-accumulator path); elements are
// individually-rounded f32 products. Validated (PASS since round 4).
__device__ __forceinline__ float np_dot128(const float* __restrict__ u,
                                           const float* __restrict__ v) {
  float r[8];
#pragma unroll
  for (int j = 0; j < 8; ++j) r[j] = fmul(u[j], v[j]);
#pragma unroll
  for (int i = 8; i < 128; i += 8) {
#pragma unroll
    for (int j = 0; j < 8; ++j) r[j] = fadd(r[j], fmul(u[i + j], v[i + j]));
  }
  return fadd(fadd(fadd(r[0], r[1]), fadd(r[2], r[3])),
              fadd(fadd(r[4], r[5]), fadd(r[6], r[7])));
}

__device__ __forceinline__ int imin(int a, int b) { return a < b ? a : b; }
__device__ __forceinline__ int imax(int a, int b) { return a > b ? a : b; }

// Branch-free sorted insert of x into ascending (k0<=k1<=k2<=k3): 7 VALU ops.
__device__ __forceinline__ void ins4(int& k0, int& k1, int& k2, int& k3, int x) {
  int a = imax(k0, x); k0 = imin(k0, x);
  int b = imax(k1, a); k1 = imin(k1, a);
  int c = imax(k2, b); k2 = imin(k2, b);
  k3 = imin(k3, c);
}

// ---------------------------------------------------------------------------
// k_prep: fused k_convert + k_c2np + all zero-init (replaces 2 memsets + 2
// kernels). Grid 64x256.
//   - cb f32 -> fp16 (x1024) cb16 + approx C2*2^20 (one wave per 16 codes)
//   - np-exact ||c||^2 per code (threads 0..4095)
//   - zero counts[4096], scal[0..2], ctrs[0..1]
// ---------------------------------------------------------------------------
__global__ __launch_bounds__(256) void k_prep(
    const float* __restrict__ cb, unsigned int* __restrict__ cb16,
    float* __restrict__ c2s, float* __restrict__ c2np,
    int* __restrict__ counts, float* __restrict__ scal,
    int* __restrict__ ctrs) {
  const int gt = blockIdx.x * 256 + threadIdx.x;   // 0..16383
  if (gt < KCB * SCB) counts[gt] = 0;
  if (gt < 3) scal[gt] = 0.0f;
  if (gt < 2) ctrs[gt] = 0;
  if (gt < KCB * SCB) {
    const float* row = cb + (size_t)gt * SUBD;
    c2np[gt] = np_dot128(row, row);
  }
  const int wave = blockIdx.x * 4 + (threadIdx.x >> 6);
  const int lane = threadIdx.x & 63;
  for (int i = 0; i < 16; ++i) {
    const int code = wave * 16 + i;   // 0..4095
    const float2 v = ((const float2*)(cb + (size_t)code * SUBD))[lane];
    float tot = fmaf(v.x, v.x, v.y * v.y);
#pragma unroll
    for (int off = 32; off > 0; off >>= 1) tot += __shfl_down(tot, off, 64);
    v2h h; h.x = (_Float16)(v.x * 1024.0f); h.y = (_Float16)(v.y * 1024.0f);
    U32H2 t; t.h = h;
    cb16[(size_t)code * 64 + lane] = t.u;
    if (lane == 0) c2s[code] = tot * 1048576.0f;  // * 2^20
  }
}

// ---------------------------------------------------------------------------
// k_scan (MFMA + packed-key top-4): D = A*B, A = codebook rows, B = z_e cols,
// via mfma_f32_32x32x16_f16. Block = 4 waves x 32 n = 128 vectors, one k,
// all 1024 codes. Ranking keys: key = ((int)score << 10) | code — cvt_i32 is
// monotonic, 1.0-unit quantization is negligible vs the ~16-40-unit f16
// approx error already tolerated; ties resolve toward smaller code, matching
// numpy argmin. Top-4 per lane kept as two branch-free 7-op sorted-insert
// sets (acc0/acc1), merged once at the end. Lane pair (hi=0/1) covers
// disjoint 512-code subsets -> 8 candidates per (n,k), same rescue guarantee
// as the validated kernel. c2 read as broadcast float4 from the L1-resident
// 16KB table (no LDS stage) -> LDS 32KB -> 5 blocks/CU.
// ---------------------------------------------------------------------------
#define SCORE(ACC, STOFF, K0, K1, K2, K3)                                    \
  {                                                                          \
    _Pragma("unroll")                                                        \
    for (int g = 0; g < 4; ++g) {                                            \
      const float4 cv = *(const float4*)(c2b + (STOFF) + hi * 4 + g * 8);    \
      const float ca[4] = {cv.x, cv.y, cv.z, cv.w};                          \
      _Pragma("unroll")                                                      \
      for (int r = 0; r < 4; ++r) {                                          \
        const float sc = fmaf(-2048.0f, (ACC)[g * 4 + r], ca[r]);            \
        const int key = ((int)sc << 10) | (tb + (STOFF) + hi * 4 + g * 8 + r); \
        ins4(K0, K1, K2, K3, key);                                           \
      }                                                                      \
    }                                                                        \
  }

__global__ __launch_bounds__(256, 4) void k_scan(
    const float* __restrict__ z_e, const unsigned int* __restrict__ cb16,
    const float* __restrict__ c2s, unsigned short* __restrict__ cand) {
  const int tid = threadIdx.x;
  const int lane = tid & 63;
  const int w = tid >> 6;
  const int hi = lane >> 5;          // row-half of the lane pair
  const int ml = lane & 31;          // n-column within the wave tile
  const int k = blockIdx.y;
  const int n = blockIdx.x * 128 + w * 32 + ml;

  __shared__ __align__(16) unsigned int ctile[2][4096];  // 2 x 16 KB (64 codes)

  const uint4* gk = (const uint4*)cb16 + (size_t)k * SCB * 16;
  const float* c2k = c2s + k * SCB;
  const int rbase = tid >> 4;                 // staging row low bits
  const int ss = (tid & 15) ^ rbase;          // pre-swizzled source slot

  // B fragments: xf[ks][j] = f16(x[n][ks*16 + hi*8 + j])  (RTNE, unscaled)
  f16x8 xf[8];
  {
    const float* xp = z_e + (size_t)n * DDIM + k * SUBD + hi * 8;
#pragma unroll
    for (int ks = 0; ks < 8; ++ks) {
      const float4 a = *(const float4*)(xp + ks * 16);
      const float4 b = *(const float4*)(xp + ks * 16 + 4);
      f16x8 h;
      h[0] = (_Float16)a.x; h[1] = (_Float16)a.y;
      h[2] = (_Float16)a.z; h[3] = (_Float16)a.w;
      h[4] = (_Float16)b.x; h[5] = (_Float16)b.y;
      h[6] = (_Float16)b.z; h[7] = (_Float16)b.w;
      xf[ks] = h;
    }
  }

  // Stage tile 0. LDS[row][p] = global[row][p ^ (row&15)]: reading
  // LDS[row][slot ^ (row&15)] returns linear data (XOR-16 bank swizzle).
  uint4 pf[4];
#pragma unroll
  for (int p = 0; p < 4; ++p) pf[p] = gk[(p * 16 + rbase) * 16 + ss];
  {
    uint4* dst = (uint4*)ctile[0];
#pragma unroll
    for (int p = 0; p < 4; ++p) dst[p * 256 + tid] = pf[p];
  }
  __syncthreads();

  int kA0 = 0x7FFFFFFF, kA1 = 0x7FFFFFFF, kA2 = 0x7FFFFFFF, kA3 = 0x7FFFFFFF;
  int kB0 = 0x7FFFFFFF, kB1 = 0x7FFFFFFF, kB2 = 0x7FFFFFFF, kB3 = 0x7FFFFFFF;

  for (int tile = 0; tile < 16; ++tile) {
    // Issue next-tile global loads early (L2-hit; consumed after compute).
    if (tile < 15) {
      const uint4* gt = gk + (size_t)(tile + 1) * 1024;
#pragma unroll
      for (int p = 0; p < 4; ++p) pf[p] = gt[(p * 16 + rbase) * 16 + ss];
    }

    const unsigned char* bufb = (const unsigned char*)ctile[tile & 1];
    f32x16 acc0, acc1;
#pragma unroll
    for (int z = 0; z < 16; ++z) { acc0[z] = 0.0f; acc1[z] = 0.0f; }

    // Two independent 32-code MFMA chains. A-frag: row = stile*32 + ml,
    // logical 16B slot = ks*2 + hi, phys slot = slot ^ (lane&15).
#pragma unroll
    for (int ks = 0; ks < 8; ++ks) {
      const int phys = (((ks * 2 + hi) ^ (lane & 15)) << 4);
      const f16x8 a0 = *(const f16x8*)(bufb + ml * 256 + phys);
      const f16x8 a1 = *(const f16x8*)(bufb + (ml + 32) * 256 + phys);
      acc0 = __builtin_amdgcn_mfma_f32_32x32x16_f16(a0, xf[ks], acc0, 0, 0, 0);
      acc1 = __builtin_amdgcn_mfma_f32_32x32x16_f16(a1, xf[ks], acc1, 0, 0, 0);
    }

    // Scores: acc reg -> code row = (reg&3) + 8*(reg>>2) + 4*hi (m74/m101).
    const int tb = tile * 64;
    const float* c2b = c2k + tb;
    SCORE(acc0, 0, kA0, kA1, kA2, kA3)
    SCORE(acc1, 32, kB0, kB1, kB2, kB3)

    if (tile < 15) {
      uint4* dst = (uint4*)ctile[(tile + 1) & 1];
#pragma unroll
      for (int p = 0; p < 4; ++p) dst[p * 256 + tid] = pf[p];
    }
    __syncthreads();
  }

  // Merge set B into set A -> top-4 of this lane's 512-code partition.
  ins4(kA0, kA1, kA2, kA3, kB0);
  ins4(kA0, kA1, kA2, kA3, kB1);
  ins4(kA0, kA1, kA2, kA3, kB2);
  ins4(kA0, kA1, kA2, kA3, kB3);

  const unsigned long long pk =
      (unsigned long long)(unsigned short)(kA0 & 1023) |
      ((unsigned long long)(unsigned short)(kA1 & 1023) << 16) |
      ((unsigned long long)(unsigned short)(kA2 & 1023) << 32) |
      ((unsigned long long)(unsigned short)(kA3 & 1023) << 48);
  *(unsigned long long*)(cand + ((size_t)(n * KCB + k)) * 8 + hi * 4) = pk;
}

// ---------------------------------------------------------------------------
// k_merge: np-exact f32 rescore of the 8 candidates per (n,k) (validated
// formula/tree). Writes final index + counts + loss partial (sum of chosen
// dists == sum (x-c)^2 up to ~1e-9 rel). Last block finalizes perplexity and
// both losses (fuses old k_perp + k_scal).
// ---------------------------------------------------------------------------
__global__ __launch_bounds__(256) void k_merge(
    const float* __restrict__ z_e, const float* __restrict__ cb,
    const unsigned short* __restrict__ cand, const float* __restrict__ c2np,
    float* __restrict__ out_idx, int* __restrict__ counts,
    float* __restrict__ scal, int* __restrict__ ctrs) {
  const int tid = threadIdx.x;
  const int g = blockIdx.x * 256 + tid;  // 0..131071
  const int n = g >> 2, k = g & 3;
  const int w = tid >> 6, lane = tid & 63;

  float4 xv[32];
  const float4* xp = (const float4*)(z_e + (size_t)n * DDIM + k * SUBD);
#pragma unroll
  for (int j = 0; j < 32; ++j) xv[j] = xp[j];
  const float* xs = (const float*)xv;
  const float A = np_dot128(xs, xs);

  const unsigned short* cp = cand + (size_t)g * 8;
  float bd = 1e30f;
  int bi = SCB;
#pragma unroll
  for (int t = 0; t < 8; ++t) {
    const int s = cp[t];
    const float* c = cb + (size_t)(k * SCB + s) * SUBD;
    const float E = np_dot128(xs, c);
    const float dist = fadd(fsub(A, fmul(2.0f, E)), c2np[k * SCB + s]);
    if (dist < bd || (dist == bd && s < bi)) { bd = dist; bi = s; }
  }

  out_idx[g] = (float)bi;
  atomicAdd(&counts[k * SCB + bi], 1);

  // Loss partial: sum of chosen distances over the block.
  float local = bd;
#pragma unroll
  for (int off = 32; off > 0; off >>= 1) local += __shfl_down(local, off, 64);
  __shared__ float red[4];
  if (lane == 0) red[w] = local;
  __syncthreads();   // also drains this block's counts atomics (vmcnt)

  __shared__ int lastf;
  if (tid == 0) {
    atomicAdd(&scal[0], (red[0] + red[1]) + (red[2] + red[3]));
    __threadfence();
    lastf = (atomicAdd(&ctrs[0], 1) == (int)gridDim.x - 1);
  }
  __syncthreads();

  if (lastf) {
    // Perplexity from final counts (agent-scope loads: atomics bypass L2-fill,
    // avoid any stale per-XCD line).
    double h = 0.0;
    for (int i = 0; i < SCB / 64; ++i) {
      const int cnt = __hip_atomic_load(&counts[w * SCB + i * 64 + lane],
                                        __ATOMIC_RELAXED, __HIP_MEMORY_SCOPE_AGENT);
      if (cnt > 0) {
        const double p = (double)cnt * (1.0 / 32768.0);
        h += p * log(p);
      }
    }
#pragma unroll
    for (int off = 32; off > 0; off >>= 1) h += __shfl_down(h, off, 64);
    __shared__ double hs[4];
    if (lane == 0) hs[w] = h;
    __syncthreads();
    if (tid == 0) {
      double perp = 0.0;
      for (int w2 = 0; w2 < 4; ++w2) perp += exp(-hs[w2]);
      scal[2] = (float)(perp * 0.25);
      const float L = __hip_atomic_load(&scal[0], __ATOMIC_RELAXED,
                                        __HIP_MEMORY_SCOPE_AGENT);
      const float m = L * (1.0f / 16777216.0f);
      scal[0] = m;   // codebook_loss
      scal[1] = m;   // commit_loss
    }
  }
}

// ---------------------------------------------------------------------------
// k_gather: coalesced gather of z_q into both output slots (pure: loss moved
// to k_merge, so no z_e read).
// ---------------------------------------------------------------------------
__global__ __launch_bounds__(256) void k_gather(
    const float* __restrict__ cb, const float* __restrict__ idxf,
    float* __restrict__ zq_st, float* __restrict__ zq_all) {
  const int base = blockIdx.x * 4096;
#pragma unroll
  for (int i = 0; i < 16; ++i) {
    const int q = base + i * 256 + threadIdx.x;
    const int nn = q >> 7;
    const int rem = q & 127;
    const int kk = rem >> 5;
    const int j4 = rem & 31;
    const int idx = (int)idxf[nn * KCB + kk];
    const float4 v = ((const float4*)cb)[(size_t)(kk * SCB + idx) * 32 + j4];
    ((float4*)zq_st)[q] = v;
    ((float4*)zq_all)[q] = v;
  }
}

extern "C" void kernel_launch(void* const* d_in, const int* in_sizes, int n_in,
                              void* d_out, int out_size, void* d_ws, size_t ws_size,
                              hipStream_t stream) {
  const float* z_e = (const float*)d_in[0];
  const float* cb = (const float*)d_in[1];
  float* out = (float*)d_out;

  float* zq_all = out + OFF_ZQ_ALL;
  int* counts = (int*)zq_all;
  float* c2s = zq_all + 4096;
  float* c2np = zq_all + 8192;
  unsigned int* cb16 = (unsigned int*)(zq_all + 12288);
  unsigned short* cand = (unsigned short*)(zq_all + 274432);
  int* ctrs = (int*)(zq_all + 800000);
  float* scal = out + OFF_SCAL;

  k_prep<<<64, 256, 0, stream>>>(cb, cb16, c2s, c2np, counts, scal, ctrs);
  dim3 gs(NVEC / 128, KCB);
  k_scan<<<gs, 256, 0, stream>>>(z_e, cb16, c2s, cand);
  k_merge<<<IDX_COUNT / 256, 256, 0, stream>>>(z_e, cb, cand, c2np, out, counts,
                                               scal, ctrs);
  k_gather<<<1024, 256, 0, stream>>>(cb, out, out + OFF_ZQ_ST, zq_all);
}

// Round 4
// 384.126 us; speedup vs baseline: 1.8765x; 1.0051x over previous
//
#include <hip/hip_runtime.h>
#include <math.h>

// Problem constants
#define NVEC  32768          // B*L = 64*512
#define DDIM  512            // CODE_DIM
#define KCB   4              // NUM_CODEBOOKS
#define SCB   1024           // CODEBOOK_SIZE
#define SUBD  128            // SUB_DIM

#define IDX_COUNT (NVEC * KCB)            // 131072
#define ZQ_COUNT  (NVEC * DDIM)           // 16777216
#define OFF_ZQ_ST  IDX_COUNT
#define OFF_ZQ_ALL (IDX_COUNT + ZQ_COUNT)
#define OFF_SCAL   (IDX_COUNT + 2 * ZQ_COUNT)

// Scratch layout inside the z_q_all output region (all consumed before
// k_gather overwrites it; d_ws unused):
//   counts : int  [4096]               at zq_all + 0       (floats)
//   c2s    : f32  [4096] (scaled 2^20) at zq_all + 4096
//   c2np   : f32  [4096] (np-exact)    at zq_all + 8192
//   cb16   : fp16 [4096][128] (x1024)  at zq_all + 12288   (1 MB, ends 274432)
//   cand   : u16  [131072][8]          at zq_all + 274432  (2 MB, ends 798720)
//   ctrs   : int  [2]                  at zq_all + 800000

typedef _Float16 v2h __attribute__((ext_vector_type(2)));
typedef _Float16 f16x8 __attribute__((ext_vector_type(8)));
typedef float f32x16 __attribute__((ext_vector_type(16)));
union U32H2 { unsigned int u; v2h h; };

// Strict (non-contractable) f32 ops replicating numpy's rounding exactly.
__device__ __forceinline__ float fmul(float a, float b) { return __fmul_rn(a, b); }
__device__ __forceinline__ float fadd(float a, float b) { return __fadd_rn(a, b); }
__device__ __forceinline__ float fsub(float a, float b) { return __fsub_rn(a, b); }

// numpy pairwise_sum for n=128 (scalar 8-accumulator path); elements are
// individually-rounded f32 products. Validated (PASS since round 4).
__device__ __forceinline__ float np_dot128(const float* __restrict__ u,
                                           const float* __restrict__ v) {
  float r[8];
#pragma unroll
  for (int j = 0; j < 8; ++j) r[j] = fmul(u[j], v[j]);
#pragma unroll
  for (int i = 8; i < 128; i += 8) {
#pragma unroll
    for (int j = 0; j < 8; ++j) r[j] = fadd(r[j], fmul(u[i + j], v[i + j]));
  }
  return fadd(fadd(fadd(r[0], r[1]), fadd(r[2], r[3])),
              fadd(fadd(r[4], r[5]), fadd(r[6], r[7])));
}

__device__ __forceinline__ int imin(int a, int b) { return a < b ? a : b; }
__device__ __forceinline__ int imax(int a, int b) { return a > b ? a : b; }

// Branch-free sorted insert of x into ascending (k0<=k1<=k2<=k3): 7 VALU ops.
__device__ __forceinline__ void ins4(int& k0, int& k1, int& k2, int& k3, int x) {
  int a = imax(k0, x); k0 = imin(k0, x);
  int b = imax(k1, a); k1 = imin(k1, a);
  int c = imax(k2, b); k2 = imin(k2, b);
  k3 = imin(k3, c);
}

// ---------------------------------------------------------------------------
// k_prep: fused convert + c2np + all zero-init. Grid 64x256.
// ---------------------------------------------------------------------------
__global__ __launch_bounds__(256) void k_prep(
    const float* __restrict__ cb, unsigned int* __restrict__ cb16,
    float* __restrict__ c2s, float* __restrict__ c2np,
    int* __restrict__ counts, float* __restrict__ scal,
    int* __restrict__ ctrs) {
  const int gt = blockIdx.x * 256 + threadIdx.x;   // 0..16383
  if (gt < KCB * SCB) counts[gt] = 0;
  if (gt < 3) scal[gt] = 0.0f;
  if (gt < 2) ctrs[gt] = 0;
  if (gt < KCB * SCB) {
    const float* row = cb + (size_t)gt * SUBD;
    c2np[gt] = np_dot128(row, row);
  }
  const int wave = blockIdx.x * 4 + (threadIdx.x >> 6);
  const int lane = threadIdx.x & 63;
  for (int i = 0; i < 16; ++i) {
    const int code = wave * 16 + i;   // 0..4095
    const float2 v = ((const float2*)(cb + (size_t)code * SUBD))[lane];
    float tot = fmaf(v.x, v.x, v.y * v.y);
#pragma unroll
    for (int off = 32; off > 0; off >>= 1) tot += __shfl_down(tot, off, 64);
    v2h h; h.x = (_Float16)(v.x * 1024.0f); h.y = (_Float16)(v.y * 1024.0f);
    U32H2 t; t.h = h;
    cb16[(size_t)code * 64 + lane] = t.u;
    if (lane == 0) c2s[code] = tot * 1048576.0f;  // * 2^20
  }
}

// ---------------------------------------------------------------------------
// k_scan (MFMA + packed-key top-4): byte-identical logic to the PASSING
// round-2 kernel; only change is plain __launch_bounds__(256) — R2's ",4"
// capped VGPR at 64 and caused 70 MB of scratch spill traffic (measured).
// ---------------------------------------------------------------------------
#define SCORE(ACC, STOFF, K0, K1, K2, K3)                                    \
  {                                                                          \
    _Pragma("unroll")                                                        \
    for (int g = 0; g < 4; ++g) {                                            \
      const float4 cv = *(const float4*)(c2b + (STOFF) + hi * 4 + g * 8);    \
      const float ca[4] = {cv.x, cv.y, cv.z, cv.w};                          \
      _Pragma("unroll")                                                      \
      for (int r = 0; r < 4; ++r) {                                          \
        const float sc = fmaf(-2048.0f, (ACC)[g * 4 + r], ca[r]);            \
        const int key = ((int)sc << 10) | (tb + (STOFF) + hi * 4 + g * 8 + r); \
        ins4(K0, K1, K2, K3, key);                                           \
      }                                                                      \
    }                                                                        \
  }

__global__ __launch_bounds__(256) void k_scan(
    const float* __restrict__ z_e, const unsigned int* __restrict__ cb16,
    const float* __restrict__ c2s, unsigned short* __restrict__ cand) {
  const int tid = threadIdx.x;
  const int lane = tid & 63;
  const int w = tid >> 6;
  const int hi = lane >> 5;          // row-half of the lane pair
  const int ml = lane & 31;          // n-column within the wave tile
  const int k = blockIdx.y;
  const int n = blockIdx.x * 128 + w * 32 + ml;

  __shared__ __align__(16) unsigned int ctile[2][4096];  // 2 x 16 KB (64 codes)

  const uint4* gk = (const uint4*)cb16 + (size_t)k * SCB * 16;
  const float* c2k = c2s + k * SCB;
  const int rbase = tid >> 4;                 // staging row low bits
  const int ss = (tid & 15) ^ rbase;          // pre-swizzled source slot

  // B fragments: xf[ks][j] = f16(x[n][ks*16 + hi*8 + j])  (RTNE, unscaled)
  f16x8 xf[8];
  {
    const float* xp = z_e + (size_t)n * DDIM + k * SUBD + hi * 8;
#pragma unroll
    for (int ks = 0; ks < 8; ++ks) {
      const float4 a = *(const float4*)(xp + ks * 16);
      const float4 b = *(const float4*)(xp + ks * 16 + 4);
      f16x8 h;
      h[0] = (_Float16)a.x; h[1] = (_Float16)a.y;
      h[2] = (_Float16)a.z; h[3] = (_Float16)a.w;
      h[4] = (_Float16)b.x; h[5] = (_Float16)b.y;
      h[6] = (_Float16)b.z; h[7] = (_Float16)b.w;
      xf[ks] = h;
    }
  }

  // Stage tile 0. LDS[row][p] = global[row][p ^ (row&15)]: reading
  // LDS[row][slot ^ (row&15)] returns linear data (XOR-16 bank swizzle).
  uint4 pf[4];
#pragma unroll
  for (int p = 0; p < 4; ++p) pf[p] = gk[(p * 16 + rbase) * 16 + ss];
  {
    uint4* dst = (uint4*)ctile[0];
#pragma unroll
    for (int p = 0; p < 4; ++p) dst[p * 256 + tid] = pf[p];
  }
  __syncthreads();

  int kA0 = 0x7FFFFFFF, kA1 = 0x7FFFFFFF, kA2 = 0x7FFFFFFF, kA3 = 0x7FFFFFFF;
  int kB0 = 0x7FFFFFFF, kB1 = 0x7FFFFFFF, kB2 = 0x7FFFFFFF, kB3 = 0x7FFFFFFF;

  for (int tile = 0; tile < 16; ++tile) {
    // Issue next-tile global loads early (L2-hit; consumed after compute).
    if (tile < 15) {
      const uint4* gt = gk + (size_t)(tile + 1) * 1024;
#pragma unroll
      for (int p = 0; p < 4; ++p) pf[p] = gt[(p * 16 + rbase) * 16 + ss];
    }

    const unsigned char* bufb = (const unsigned char*)ctile[tile & 1];
    f32x16 acc0, acc1;
#pragma unroll
    for (int z = 0; z < 16; ++z) { acc0[z] = 0.0f; acc1[z] = 0.0f; }

    // Two independent 32-code MFMA chains. A-frag: row = stile*32 + ml,
    // logical 16B slot = ks*2 + hi, phys slot = slot ^ (lane&15).
#pragma unroll
    for (int ks = 0; ks < 8; ++ks) {
      const int phys = (((ks * 2 + hi) ^ (lane & 15)) << 4);
      const f16x8 a0 = *(const f16x8*)(bufb + ml * 256 + phys);
      const f16x8 a1 = *(const f16x8*)(bufb + (ml + 32) * 256 + phys);
      acc0 = __builtin_amdgcn_mfma_f32_32x32x16_f16(a0, xf[ks], acc0, 0, 0, 0);
      acc1 = __builtin_amdgcn_mfma_f32_32x32x16_f16(a1, xf[ks], acc1, 0, 0, 0);
    }

    // Scores: acc reg -> code row = (reg&3) + 8*(reg>>2) + 4*hi (m74/m101).
    const int tb = tile * 64;
    const float* c2b = c2k + tb;
    SCORE(acc0, 0, kA0, kA1, kA2, kA3)
    SCORE(acc1, 32, kB0, kB1, kB2, kB3)

    if (tile < 15) {
      uint4* dst = (uint4*)ctile[(tile + 1) & 1];
#pragma unroll
      for (int p = 0; p < 4; ++p) dst[p * 256 + tid] = pf[p];
    }
    __syncthreads();
  }

  // Merge set B into set A -> top-4 of this lane's 512-code partition.
  ins4(kA0, kA1, kA2, kA3, kB0);
  ins4(kA0, kA1, kA2, kA3, kB1);
  ins4(kA0, kA1, kA2, kA3, kB2);
  ins4(kA0, kA1, kA2, kA3, kB3);

  const unsigned long long pk =
      (unsigned long long)(unsigned short)(kA0 & 1023) |
      ((unsigned long long)(unsigned short)(kA1 & 1023) << 16) |
      ((unsigned long long)(unsigned short)(kA2 & 1023) << 32) |
      ((unsigned long long)(unsigned short)(kA3 & 1023) << 48);
  *(unsigned long long*)(cand + ((size_t)(n * KCB + k)) * 8 + hi * 4) = pk;
}

// ---------------------------------------------------------------------------
// k_merge: np-exact f32 rescore of the 8 candidates per (n,k) (validated
// formula/tree, serial — the exact round-2 PASSING version). Writes final
// index + counts + loss partial. Last block finalizes perplexity + losses.
// ---------------------------------------------------------------------------
__global__ __launch_bounds__(256) void k_merge(
    const float* __restrict__ z_e, const float* __restrict__ cb,
    const unsigned short* __restrict__ cand, const float* __restrict__ c2np,
    float* __restrict__ out_idx, int* __restrict__ counts,
    float* __restrict__ scal, int* __restrict__ ctrs) {
  const int tid = threadIdx.x;
  const int g = blockIdx.x * 256 + tid;  // 0..131071
  const int n = g >> 2, k = g & 3;
  const int w = tid >> 6, lane = tid & 63;

  float4 xv[32];
  const float4* xp = (const float4*)(z_e + (size_t)n * DDIM + k * SUBD);
#pragma unroll
  for (int j = 0; j < 32; ++j) xv[j] = xp[j];
  const float* xs = (const float*)xv;
  const float A = np_dot128(xs, xs);

  const unsigned short* cp = cand + (size_t)g * 8;
  float bd = 1e30f;
  int bi = SCB;
#pragma unroll
  for (int t = 0; t < 8; ++t) {
    const int s = cp[t];
    const float* c = cb + (size_t)(k * SCB + s) * SUBD;
    const float E = np_dot128(xs, c);
    const float dist = fadd(fsub(A, fmul(2.0f, E)), c2np[k * SCB + s]);
    if (dist < bd || (dist == bd && s < bi)) { bd = dist; bi = s; }
  }

  out_idx[g] = (float)bi;
  atomicAdd(&counts[k * SCB + bi], 1);

  // Loss partial: sum of chosen distances over the block.
  float local = bd;
#pragma unroll
  for (int off = 32; off > 0; off >>= 1) local += __shfl_down(local, off, 64);
  __shared__ float red[4];
  if (lane == 0) red[w] = local;
  __syncthreads();   // also drains this block's counts atomics

  __shared__ int lastf;
  if (tid == 0) {
    atomicAdd(&scal[0], (red[0] + red[1]) + (red[2] + red[3]));
    __threadfence();
    lastf = (atomicAdd(&ctrs[0], 1) == (int)gridDim.x - 1);
  }
  __syncthreads();

  if (lastf) {
    double h = 0.0;
    for (int i = 0; i < SCB / 64; ++i) {
      const int cnt = __hip_atomic_load(&counts[w * SCB + i * 64 + lane],
                                        __ATOMIC_RELAXED, __HIP_MEMORY_SCOPE_AGENT);
      if (cnt > 0) {
        const double p = (double)cnt * (1.0 / 32768.0);
        h += p * log(p);
      }
    }
#pragma unroll
    for (int off = 32; off > 0; off >>= 1) h += __shfl_down(h, off, 64);
    __shared__ double hs[4];
    if (lane == 0) hs[w] = h;
    __syncthreads();
    if (tid == 0) {
      double perp = 0.0;
      for (int w2 = 0; w2 < 4; ++w2) perp += exp(-hs[w2]);
      scal[2] = (float)(perp * 0.25);
      const float L = __hip_atomic_load(&scal[0], __ATOMIC_RELAXED,
                                        __HIP_MEMORY_SCOPE_AGENT);
      const float m = L * (1.0f / 16777216.0f);
      scal[0] = m;   // codebook_loss
      scal[1] = m;   // commit_loss
    }
  }
}

// ---------------------------------------------------------------------------
// k_gather: coalesced gather of z_q into both output slots.
// ---------------------------------------------------------------------------
__global__ __launch_bounds__(256) void k_gather(
    const float* __restrict__ cb, const float* __restrict__ idxf,
    float* __restrict__ zq_st, float* __restrict__ zq_all) {
  const int base = blockIdx.x * 4096;
#pragma unroll
  for (int i = 0; i < 16; ++i) {
    const int q = base + i * 256 + threadIdx.x;
    const int nn = q >> 7;
    const int rem = q & 127;
    const int kk = rem >> 5;
    const int j4 = rem & 31;
    const int idx = (int)idxf[nn * KCB + kk];
    const float4 v = ((const float4*)cb)[(size_t)(kk * SCB + idx) * 32 + j4];
    ((float4*)zq_st)[q] = v;
    ((float4*)zq_all)[q] = v;
  }
}

extern "C" void kernel_launch(void* const* d_in, const int* in_sizes, int n_in,
                              void* d_out, int out_size, void* d_ws, size_t ws_size,
                              hipStream_t stream) {
  const float* z_e = (const float*)d_in[0];
  const float* cb = (const float*)d_in[1];
  float* out = (float*)d_out;

  float* zq_all = out + OFF_ZQ_ALL;
  int* counts = (int*)zq_all;
  float* c2s = zq_all + 4096;
  float* c2np = zq_all + 8192;
  unsigned int* cb16 = (unsigned int*)(zq_all + 12288);
  unsigned short* cand = (unsigned short*)(zq_all + 274432);
  int* ctrs = (int*)(zq_all + 800000);
  float* scal = out + OFF_SCAL;

  k_prep<<<64, 256, 0, stream>>>(cb, cb16, c2s, c2np, counts, scal, ctrs);
  dim3 gs(NVEC / 128, KCB);
  k_scan<<<gs, 256, 0, stream>>>(z_e, cb16, c2s, cand);
  k_merge<<<IDX_COUNT / 256, 256, 0, stream>>>(z_e, cb, cand, c2np, out, counts,
                                               scal, ctrs);
  k_gather<<<1024, 256, 0, stream>>>(cb, out, out + OFF_ZQ_ST, zq_all);
}

// Round 5
// 351.628 us; speedup vs baseline: 2.0499x; 1.0924x over previous
//
#include <hip/hip_runtime.h>
#include <math.h>

// Problem constants
#define NVEC  32768          // B*L = 64*512
#define DDIM  512            // CODE_DIM
#define KCB   4              // NUM_CODEBOOKS
#define SCB   1024           // CODEBOOK_SIZE
#define SUBD  128            // SUB_DIM

#define IDX_COUNT (NVEC * KCB)            // 131072
#define ZQ_COUNT  (NVEC * DDIM)           // 16777216
#define OFF_ZQ_ST  IDX_COUNT
#define OFF_ZQ_ALL (IDX_COUNT + ZQ_COUNT)
#define OFF_SCAL   (IDX_COUNT + 2 * ZQ_COUNT)

// Scratch layout inside the z_q_all output region (all consumed before
// k_gather overwrites it; d_ws unused):
//   counts : int  [4096]               at zq_all + 0       (floats)
//   c2s    : f32  [4096] (scaled 2^20) at zq_all + 4096
//   c2np   : f32  [4096] (np-exact)    at zq_all + 8192
//   cb16   : fp16 [4096][128] (x1024)  at zq_all + 12288   (1 MB, ends 274432)
//   cand   : u16  [131072][8]          at zq_all + 274432  (2 MB, ends 798720)
//   ctrs   : int  [2]                  at zq_all + 800000

typedef _Float16 v2h __attribute__((ext_vector_type(2)));
typedef _Float16 f16x8 __attribute__((ext_vector_type(8)));
typedef float f32x16 __attribute__((ext_vector_type(16)));
union U32H2 { unsigned int u; v2h h; };

// Strict (non-contractable) f32 ops replicating numpy's rounding exactly.
__device__ __forceinline__ float fmul(float a, float b) { return __fmul_rn(a, b); }
__device__ __forceinline__ float fadd(float a, float b) { return __fadd_rn(a, b); }
__device__ __forceinline__ float fsub(float a, float b) { return __fsub_rn(a, b); }

// numpy pairwise_sum for n=128 (scalar 8-accumulator path); elements are
// individually-rounded f32 products. Validated (PASS since round 4).
__device__ __forceinline__ float np_dot128(const float* __restrict__ u,
                                           const float* __restrict__ v) {
  float r[8];
#pragma unroll
  for (int j = 0; j < 8; ++j) r[j] = fmul(u[j], v[j]);
#pragma unroll
  for (int i = 8; i < 128; i += 8) {
#pragma unroll
    for (int j = 0; j < 8; ++j) r[j] = fadd(r[j], fmul(u[i + j], v[i + j]));
  }
  return fadd(fadd(fadd(r[0], r[1]), fadd(r[2], r[3])),
              fadd(fadd(r[4], r[5]), fadd(r[6], r[7])));
}

__device__ __forceinline__ int imin(int a, int b) { return a < b ? a : b; }
__device__ __forceinline__ int imax(int a, int b) { return a > b ? a : b; }

// Branch-free sorted insert of x into ascending (k0<=k1<=k2<=k3): 7 VALU ops.
__device__ __forceinline__ void ins4(int& k0, int& k1, int& k2, int& k3, int x) {
  int a = imax(k0, x); k0 = imin(k0, x);
  int b = imax(k1, a); k1 = imin(k1, a);
  int c = imax(k2, b); k2 = imin(k2, b);
  k3 = imin(k3, c);
}

// ---------------------------------------------------------------------------
// k_prep: fused convert + c2np + all zero-init. Grid 64x256.
// ---------------------------------------------------------------------------
__global__ __launch_bounds__(256) void k_prep(
    const float* __restrict__ cb, unsigned int* __restrict__ cb16,
    float* __restrict__ c2s, float* __restrict__ c2np,
    int* __restrict__ counts, float* __restrict__ scal,
    int* __restrict__ ctrs) {
  const int gt = blockIdx.x * 256 + threadIdx.x;   // 0..16383
  if (gt < KCB * SCB) counts[gt] = 0;
  if (gt < 3) scal[gt] = 0.0f;
  if (gt < 2) ctrs[gt] = 0;
  if (gt < KCB * SCB) {
    const float* row = cb + (size_t)gt * SUBD;
    c2np[gt] = np_dot128(row, row);
  }
  const int wave = blockIdx.x * 4 + (threadIdx.x >> 6);
  const int lane = threadIdx.x & 63;
  for (int i = 0; i < 16; ++i) {
    const int code = wave * 16 + i;   // 0..4095
    const float2 v = ((const float2*)(cb + (size_t)code * SUBD))[lane];
    float tot = fmaf(v.x, v.x, v.y * v.y);
#pragma unroll
    for (int off = 32; off > 0; off >>= 1) tot += __shfl_down(tot, off, 64);
    v2h h; h.x = (_Float16)(v.x * 1024.0f); h.y = (_Float16)(v.y * 1024.0f);
    U32H2 t; t.h = h;
    cb16[(size_t)code * 64 + lane] = t.u;
    if (lane == 0) c2s[code] = tot * 1048576.0f;  // * 2^20
  }
}

// ---------------------------------------------------------------------------
// k_scan (MFMA + packed-key top-4 + async LDS staging): logic identical to
// the PASSING round-4 kernel; the ONLY change is staging via
// __builtin_amdgcn_global_load_lds width=16 (removes the pf[4] register
// prefetch block that was spilling ~40 MB of scratch traffic).
// Swizzle discipline (rule #21): LDS dest LINEAR in tid (wave-uniform base +
// lane*16), global SOURCE pre-swizzled (ss), ds_read applies the same XOR
// (phys) — staged bytes are bit-identical to the reg-staged version.
// ---------------------------------------------------------------------------
#define SCORE(ACC, STOFF, K0, K1, K2, K3)                                    \
  {                                                                          \
    _Pragma("unroll")                                                        \
    for (int g = 0; g < 4; ++g) {                                            \
      const float4 cv = *(const float4*)(c2b + (STOFF) + hi * 4 + g * 8);    \
      const float ca[4] = {cv.x, cv.y, cv.z, cv.w};                          \
      _Pragma("unroll")                                                      \
      for (int r = 0; r < 4; ++r) {                                          \
        const float sc = fmaf(-2048.0f, (ACC)[g * 4 + r], ca[r]);            \
        const int key = ((int)sc << 10) | (tb + (STOFF) + hi * 4 + g * 8 + r); \
        ins4(K0, K1, K2, K3, key);                                           \
      }                                                                      \
    }                                                                        \
  }

// One 16 KB tile: per wave w, chunk p covers uint4 slots [p*256+w*64,
// p*256+w*64+64). Lane l supplies the 16B at global index
// (p*16 + rbase)*16 + ss (pre-swizzled source).
__device__ __forceinline__ void stage_tile(const uint4* __restrict__ gsrc,
                                           unsigned int* lds_u32,
                                           int w, int rbase, int ss) {
#pragma unroll
  for (int p = 0; p < 4; ++p) {
    const uint4* src = gsrc + (size_t)((p * 16 + rbase) * 16 + ss);
    unsigned int* dst = lds_u32 + (p * 256 + w * 64) * 4;  // wave-uniform
    __builtin_amdgcn_global_load_lds(
        (const __attribute__((address_space(1))) unsigned int*)src,
        (__attribute__((address_space(3))) unsigned int*)dst, 16, 0, 0);
  }
}

__global__ __launch_bounds__(256) void k_scan(
    const float* __restrict__ z_e, const unsigned int* __restrict__ cb16,
    const float* __restrict__ c2s, unsigned short* __restrict__ cand) {
  const int tid = threadIdx.x;
  const int lane = tid & 63;
  const int w = tid >> 6;
  const int hi = lane >> 5;          // row-half of the lane pair
  const int ml = lane & 31;          // n-column within the wave tile
  const int k = blockIdx.y;
  const int n = blockIdx.x * 128 + w * 32 + ml;

  __shared__ __align__(16) unsigned int ctile[2][4096];  // 2 x 16 KB (64 codes)

  const uint4* gk = (const uint4*)cb16 + (size_t)k * SCB * 16;
  const float* c2k = c2s + k * SCB;
  const int rbase = tid >> 4;                 // staging row low bits
  const int ss = (tid & 15) ^ rbase;          // pre-swizzled source slot

  // B fragments: xf[ks][j] = f16(x[n][ks*16 + hi*8 + j])  (RTNE, unscaled)
  f16x8 xf[8];
  {
    const float* xp = z_e + (size_t)n * DDIM + k * SUBD + hi * 8;
#pragma unroll
    for (int ks = 0; ks < 8; ++ks) {
      const float4 a = *(const float4*)(xp + ks * 16);
      const float4 b = *(const float4*)(xp + ks * 16 + 4);
      f16x8 h;
      h[0] = (_Float16)a.x; h[1] = (_Float16)a.y;
      h[2] = (_Float16)a.z; h[3] = (_Float16)a.w;
      h[4] = (_Float16)b.x; h[5] = (_Float16)b.y;
      h[6] = (_Float16)b.z; h[7] = (_Float16)b.w;
      xf[ks] = h;
    }
  }

  // Stage tile 0 (async), then barrier (drains vmcnt).
  stage_tile(gk, ctile[0], w, rbase, ss);
  __syncthreads();

  int kA0 = 0x7FFFFFFF, kA1 = 0x7FFFFFFF, kA2 = 0x7FFFFFFF, kA3 = 0x7FFFFFFF;
  int kB0 = 0x7FFFFFFF, kB1 = 0x7FFFFFFF, kB2 = 0x7FFFFFFF, kB3 = 0x7FFFFFFF;

  for (int tile = 0; tile < 16; ++tile) {
    // Async-stage next tile into the other buffer; in flight during compute,
    // drained by the vmcnt(0) the compiler emits before the end-of-loop
    // barrier.
    if (tile < 15)
      stage_tile(gk + (size_t)(tile + 1) * 1024, ctile[(tile + 1) & 1],
                 w, rbase, ss);

    const unsigned char* bufb = (const unsigned char*)ctile[tile & 1];
    f32x16 acc0, acc1;
#pragma unroll
    for (int z = 0; z < 16; ++z) { acc0[z] = 0.0f; acc1[z] = 0.0f; }

    // Two independent 32-code MFMA chains. A-frag: row = stile*32 + ml,
    // logical 16B slot = ks*2 + hi, phys slot = slot ^ (lane&15).
#pragma unroll
    for (int ks = 0; ks < 8; ++ks) {
      const int phys = (((ks * 2 + hi) ^ (lane & 15)) << 4);
      const f16x8 a0 = *(const f16x8*)(bufb + ml * 256 + phys);
      const f16x8 a1 = *(const f16x8*)(bufb + (ml + 32) * 256 + phys);
      acc0 = __builtin_amdgcn_mfma_f32_32x32x16_f16(a0, xf[ks], acc0, 0, 0, 0);
      acc1 = __builtin_amdgcn_mfma_f32_32x32x16_f16(a1, xf[ks], acc1, 0, 0, 0);
    }

    // Scores: acc reg -> code row = (reg&3) + 8*(reg>>2) + 4*hi (m74/m101).
    const int tb = tile * 64;
    const float* c2b = c2k + tb;
    SCORE(acc0, 0, kA0, kA1, kA2, kA3)
    SCORE(acc1, 32, kB0, kB1, kB2, kB3)

    __syncthreads();
  }

  // Merge set B into set A -> top-4 of this lane's 512-code partition.
  ins4(kA0, kA1, kA2, kA3, kB0);
  ins4(kA0, kA1, kA2, kA3, kB1);
  ins4(kA0, kA1, kA2, kA3, kB2);
  ins4(kA0, kA1, kA2, kA3, kB3);

  const unsigned long long pk =
      (unsigned long long)(unsigned short)(kA0 & 1023) |
      ((unsigned long long)(unsigned short)(kA1 & 1023) << 16) |
      ((unsigned long long)(unsigned short)(kA2 & 1023) << 32) |
      ((unsigned long long)(unsigned short)(kA3 & 1023) << 48);
  *(unsigned long long*)(cand + ((size_t)(n * KCB + k)) * 8 + hi * 4) = pk;
}

// ---------------------------------------------------------------------------
// k_merge: np-exact f32 rescore of the 8 candidates per (n,k) (validated
// formula/tree, serial — the exact round-2/4 PASSING version). Writes final
// index + counts + loss partial. Last block finalizes perplexity + losses.
// ---------------------------------------------------------------------------
__global__ __launch_bounds__(256) void k_merge(
    const float* __restrict__ z_e, const float* __restrict__ cb,
    const unsigned short* __restrict__ cand, const float* __restrict__ c2np,
    float* __restrict__ out_idx, int* __restrict__ counts,
    float* __restrict__ scal, int* __restrict__ ctrs) {
  const int tid = threadIdx.x;
  const int g = blockIdx.x * 256 + tid;  // 0..131071
  const int n = g >> 2, k = g & 3;
  const int w = tid >> 6, lane = tid & 63;

  float4 xv[32];
  const float4* xp = (const float4*)(z_e + (size_t)n * DDIM + k * SUBD);
#pragma unroll
  for (int j = 0; j < 32; ++j) xv[j] = xp[j];
  const float* xs = (const float*)xv;
  const float A = np_dot128(xs, xs);

  const unsigned short* cp = cand + (size_t)g * 8;
  float bd = 1e30f;
  int bi = SCB;
#pragma unroll
  for (int t = 0; t < 8; ++t) {
    const int s = cp[t];
    const float* c = cb + (size_t)(k * SCB + s) * SUBD;
    const float E = np_dot128(xs, c);
    const float dist = fadd(fsub(A, fmul(2.0f, E)), c2np[k * SCB + s]);
    if (dist < bd || (dist == bd && s < bi)) { bd = dist; bi = s; }
  }

  out_idx[g] = (float)bi;
  atomicAdd(&counts[k * SCB + bi], 1);

  // Loss partial: sum of chosen distances over the block.
  float local = bd;
#pragma unroll
  for (int off = 32; off > 0; off >>= 1) local += __shfl_down(local, off, 64);
  __shared__ float red[4];
  if (lane == 0) red[w] = local;
  __syncthreads();   // also drains this block's counts atomics

  __shared__ int lastf;
  if (tid == 0) {
    atomicAdd(&scal[0], (red[0] + red[1]) + (red[2] + red[3]));
    __threadfence();
    lastf = (atomicAdd(&ctrs[0], 1) == (int)gridDim.x - 1);
  }
  __syncthreads();

  if (lastf) {
    double h = 0.0;
    for (int i = 0; i < SCB / 64; ++i) {
      const int cnt = __hip_atomic_load(&counts[w * SCB + i * 64 + lane],
                                        __ATOMIC_RELAXED, __HIP_MEMORY_SCOPE_AGENT);
      if (cnt > 0) {
        const double p = (double)cnt * (1.0 / 32768.0);
        h += p * log(p);
      }
    }
#pragma unroll
    for (int off = 32; off > 0; off >>= 1) h += __shfl_down(h, off, 64);
    __shared__ double hs[4];
    if (lane == 0) hs[w] = h;
    __syncthreads();
    if (tid == 0) {
      double perp = 0.0;
      for (int w2 = 0; w2 < 4; ++w2) perp += exp(-hs[w2]);
      scal[2] = (float)(perp * 0.25);
      const float L = __hip_atomic_load(&scal[0], __ATOMIC_RELAXED,
                                        __HIP_MEMORY_SCOPE_AGENT);
      const float m = L * (1.0f / 16777216.0f);
      scal[0] = m;   // codebook_loss
      scal[1] = m;   // commit_loss
    }
  }
}

// ---------------------------------------------------------------------------
// k_gather: coalesced gather of z_q into both output slots.
// ---------------------------------------------------------------------------
__global__ __launch_bounds__(256) void k_gather(
    const float* __restrict__ cb, const float* __restrict__ idxf,
    float* __restrict__ zq_st, float* __restrict__ zq_all) {
  const int base = blockIdx.x * 4096;
#pragma unroll
  for (int i = 0; i < 16; ++i) {
    const int q = base + i * 256 + threadIdx.x;
    const int nn = q >> 7;
    const int rem = q & 127;
    const int kk = rem >> 5;
    const int j4 = rem & 31;
    const int idx = (int)idxf[nn * KCB + kk];
    const float4 v = ((const float4*)cb)[(size_t)(kk * SCB + idx) * 32 + j4];
    ((float4*)zq_st)[q] = v;
    ((float4*)zq_all)[q] = v;
  }
}

extern "C" void kernel_launch(void* const* d_in, const int* in_sizes, int n_in,
                              void* d_out, int out_size, void* d_ws, size_t ws_size,
                              hipStream_t stream) {
  const float* z_e = (const float*)d_in[0];
  const float* cb = (const float*)d_in[1];
  float* out = (float*)d_out;

  float* zq_all = out + OFF_ZQ_ALL;
  int* counts = (int*)zq_all;
  float* c2s = zq_all + 4096;
  float* c2np = zq_all + 8192;
  unsigned int* cb16 = (unsigned int*)(zq_all + 12288);
  unsigned short* cand = (unsigned short*)(zq_all + 274432);
  int* ctrs = (int*)(zq_all + 800000);
  float* scal = out + OFF_SCAL;

  k_prep<<<64, 256, 0, stream>>>(cb, cb16, c2s, c2np, counts, scal, ctrs);
  dim3 gs(NVEC / 128, KCB);
  k_scan<<<gs, 256, 0, stream>>>(z_e, cb16, c2s, cand);
  k_merge<<<IDX_COUNT / 256, 256, 0, stream>>>(z_e, cb, cand, c2np, out, counts,
                                               scal, ctrs);
  k_gather<<<1024, 256, 0, stream>>>(cb, out, out + OFF_ZQ_ST, zq_all);
}